// Round 2
// baseline (119195.508 us; speedup 1.0000x reference)
//
#include <hip/hip_runtime.h>

// Problem sizes (fixed).
#define T_STEPS 65536

typedef float f2 __attribute__((ext_vector_type(2)));
typedef float f4 __attribute__((ext_vector_type(4)));

__device__ __forceinline__ float sigmoid_f(float x) {
  float e = __expf(-x);
  return __builtin_amdgcn_rcpf(1.0f + e);
}
__device__ __forceinline__ float tanh_f(float x) {
  float e = __expf(-2.0f * x);
  return (1.0f - e) * __builtin_amdgcn_rcpf(1.0f + e);
}

// LDS-only barrier: waits DS ops, does NOT drain vmcnt -> global prefetch
// loads stay in flight across steps (the R0 kernel paid ~2 HBM-latency
// drains per step via __syncthreads' implicit vmcnt(0)).
__device__ __forceinline__ void bar_lds() {
  asm volatile("s_waitcnt lgkmcnt(0)\n\ts_barrier" ::: "memory");
}

// ---------------------------------------------------------------------------
// Generic K=128 GEMM: OUT[T][N] = act(IN[T][128] @ W[128][N] + bias[N])
// block = 256 threads, 32 rows/block. col-thread ct (64) x row-thread rt (4).
// ---------------------------------------------------------------------------
__global__ __launch_bounds__(256)
void gemm_k128(const float* __restrict__ IN, const float* __restrict__ W,
               const float* __restrict__ bias, float* __restrict__ OUT,
               int N, int relu) {
  __shared__ __align__(16) float in_t[32][132];  // +4 pad: kills bank conflicts
  const int tid = threadIdx.x;
  const int ct = tid & 63;
  const int rt = tid >> 6;               // == wave index
  const int R0 = blockIdx.x * 32;

  // Stage IN tile [32][128] (coalesced float4).
  const f4* src = (const f4*)(IN + (size_t)R0 * 128);
#pragma unroll
  for (int q = 0; q < 4; ++q) {
    int f4i = tid + 256 * q;
    int r = f4i >> 5, c4 = f4i & 31;
    f4 v = src[f4i];
    *(f4*)&in_t[r][c4 * 4] = v;
  }
  __syncthreads();

  f2 acc[8][4];
#pragma unroll
  for (int r = 0; r < 8; ++r)
#pragma unroll
    for (int m = 0; m < 4; ++m) acc[r][m] = (f2)0.0f;

  for (int kp = 0; kp < 64; ++kp) {
    f2 iv[8];
#pragma unroll
    for (int r = 0; r < 8; ++r)
      iv[r] = *(const f2*)&in_t[rt * 8 + r][2 * kp];  // same addr across wave: broadcast
    f2 wv[4];
#pragma unroll
    for (int m = 0; m < 4; ++m) {
      int c = ct + 64 * m;
      if (c < N) {
        wv[m].x = W[(2 * kp) * N + c];
        wv[m].y = W[(2 * kp + 1) * N + c];
      } else {
        wv[m] = (f2)0.0f;
      }
    }
#pragma unroll
    for (int r = 0; r < 8; ++r)
#pragma unroll
      for (int m = 0; m < 4; ++m)
        acc[r][m] = __builtin_elementwise_fma(iv[r], wv[m], acc[r][m]);
  }

#pragma unroll
  for (int m = 0; m < 4; ++m) {
    int c = ct + 64 * m;
    if (c < N) {
      float b = bias[c];
#pragma unroll
      for (int r = 0; r < 8; ++r) {
        float v = acc[r][m].x + acc[r][m].y + b;
        if (relu) v = fmaxf(v, 0.0f);
        OUT[(size_t)(R0 + rt * 8 + r) * N + c] = v;
      }
    }
  }
}

// ---------------------------------------------------------------------------
// GRU scan: single block, 256 threads (4 waves). Per step t:
//   g = sigmoid(A[t] + h @ Wgh); r,u = split(g)
//   c = tanh(CX[t] + (r*h) @ Wch)
//   h' = u*h + (1-u)*c
// Thread i owns gate column i (64 float2 weights pinned in regs) and
// candidate column i>>1, K-half i&1 (32 float2 weights pinned in regs).
// h double-buffered in LDS; 2 LDS-only barriers per step (no vmcnt drain).
// A/CX streams prefetched in 8-step register blocks, one block ahead.
// ---------------------------------------------------------------------------
#define GRU_STEP(TT, RB, AVAL, CVIN)                                          \
  do {                                                                        \
    const f4* hp = (const f4*)hbuf[RB];                                       \
    f2 a0 = (f2)0.0f, a1 = (f2)0.0f, a2 = (f2)0.0f, a3 = (f2)0.0f;            \
    _Pragma("unroll")                                                         \
    for (int m = 0; m < 8; ++m) {                                             \
      f4 ha = hp[4 * m + 0], hb = hp[4 * m + 1];                              \
      f4 hc = hp[4 * m + 2], hd = hp[4 * m + 3];                              \
      a0 = __builtin_elementwise_fma(ha.xy, wg[8 * m + 0], a0);               \
      a1 = __builtin_elementwise_fma(ha.zw, wg[8 * m + 1], a1);               \
      a2 = __builtin_elementwise_fma(hb.xy, wg[8 * m + 2], a2);               \
      a3 = __builtin_elementwise_fma(hb.zw, wg[8 * m + 3], a3);               \
      a0 = __builtin_elementwise_fma(hc.xy, wg[8 * m + 4], a0);               \
      a1 = __builtin_elementwise_fma(hc.zw, wg[8 * m + 5], a1);               \
      a2 = __builtin_elementwise_fma(hd.xy, wg[8 * m + 6], a2);               \
      a3 = __builtin_elementwise_fma(hd.zw, wg[8 * m + 7], a3);               \
    }                                                                         \
    f2 asum = (a0 + a1) + (a2 + a3);                                          \
    float g = sigmoid_f(asum.x + asum.y + (AVAL));                            \
    if (i < 128) rh[i] = g * hbuf[RB][i];                                     \
    else ug[i - 128] = g;                                                     \
    bar_lds();                                                                \
    const f4* rp = (const f4*)&rh[k0];                                        \
    f2 c0 = (f2)0.0f, c1 = (f2)0.0f, c2 = (f2)0.0f, c3 = (f2)0.0f;            \
    _Pragma("unroll")                                                         \
    for (int m = 0; m < 4; ++m) {                                             \
      f4 ra = rp[4 * m + 0], rb_ = rp[4 * m + 1];                             \
      f4 rc = rp[4 * m + 2], rd = rp[4 * m + 3];                              \
      c0 = __builtin_elementwise_fma(ra.xy, wc[8 * m + 0], c0);               \
      c1 = __builtin_elementwise_fma(ra.zw, wc[8 * m + 1], c1);               \
      c2 = __builtin_elementwise_fma(rb_.xy, wc[8 * m + 2], c2);              \
      c3 = __builtin_elementwise_fma(rb_.zw, wc[8 * m + 3], c3);              \
      c0 = __builtin_elementwise_fma(rc.xy, wc[8 * m + 4], c0);               \
      c1 = __builtin_elementwise_fma(rc.zw, wc[8 * m + 5], c1);               \
      c2 = __builtin_elementwise_fma(rd.xy, wc[8 * m + 6], c2);               \
      c3 = __builtin_elementwise_fma(rd.zw, wc[8 * m + 7], c3);               \
    }                                                                         \
    f2 csum = (c0 + c1) + (c2 + c3);                                          \
    float ps = csum.x + csum.y;                                               \
    ps += __shfl_xor(ps, 1);                                                  \
    float cand = tanh_f(ps + (CVIN));                                         \
    float u = ug[cc];                                                         \
    float hold = hbuf[RB][cc];                                                \
    float hn = u * hold + (1.0f - u) * cand;                                  \
    if ((i & 1) == 0) {                                                       \
      hbuf[(RB) ^ 1][cc] = hn;                                                \
      hout[(size_t)(TT) * 128 + cc] = hn;                                     \
    }                                                                         \
    bar_lds();                                                                \
  } while (0)

__global__ __launch_bounds__(256, 1)
void gru_scan(const float* __restrict__ A,    // [T][256] x-part gate preacts (+bias)
              const float* __restrict__ CX,   // [T][128] x-part cand preacts (+bias)
              const float* __restrict__ Wgh,  // [128][256] h rows of gates kernel
              const float* __restrict__ Wch,  // [128][128] h rows of cand kernel
              float* __restrict__ hout,       // [T][128]
              float* __restrict__ hfinal) {   // [128]
  __shared__ __align__(16) float hbuf[2][128];
  __shared__ __align__(16) float rh[128];
  __shared__ __align__(16) float ug[128];
  const int i = threadIdx.x;
  const int cc = i >> 1;
  const int k0 = (i & 1) * 64;

  // Pin weight columns in registers (coalesced loads).
  f2 wg[64];
#pragma unroll
  for (int m = 0; m < 64; ++m) {
    wg[m].x = Wgh[(2 * m) * 256 + i];
    wg[m].y = Wgh[(2 * m + 1) * 256 + i];
  }
  f2 wc[32];
#pragma unroll
  for (int m = 0; m < 32; ++m) {
    wc[m].x = Wch[(k0 + 2 * m) * 128 + cc];
    wc[m].y = Wch[(k0 + 2 * m + 1) * 128 + cc];
  }
  if (i < 128) { hbuf[0][i] = 0.0f; hbuf[1][i] = 0.0f; }

  const float* Ab = A + i;    // per-thread gate-col stream, stride 256
  const float* Cb = CX + cc;  // per-thread cand-col stream, stride 128

  float acur[8], ccur[8], anxt[8], cnxt[8];
#pragma unroll
  for (int q = 0; q < 8; ++q) {
    acur[q] = Ab[(size_t)q * 256];
    ccur[q] = Cb[(size_t)q * 128];
  }
  __syncthreads();  // covers hbuf init + weight loads (once)

  for (int t0 = 0; t0 < T_STEPS; t0 += 8) {
    // Issue next block's stream loads; consumed 8 steps (~3k cyc) later.
    const size_t nb = (t0 + 8 < T_STEPS) ? (size_t)(t0 + 8) : 0;  // wrap: harmless
#pragma unroll
    for (int q = 0; q < 8; ++q) {
      anxt[q] = Ab[(nb + q) * 256];
      cnxt[q] = Cb[(nb + q) * 128];
    }
#pragma unroll
    for (int q = 0; q < 8; ++q) {
      GRU_STEP(t0 + q, q & 1, acur[q], ccur[q]);
    }
#pragma unroll
    for (int q = 0; q < 8; ++q) { acur[q] = anxt[q]; ccur[q] = cnxt[q]; }
  }

  // Final h: last step (t odd) wrote hbuf[0].
  bar_lds();
  if (i < 128) hfinal[i] = hbuf[0][i];
}

// ---------------------------------------------------------------------------
// Final projections: logits = PI @ Wp + bp, value = V @ Wv + bv.
// block = 256 threads, 128 rows/block; tiles staged in LDS (pad 101 vs 100).
// ---------------------------------------------------------------------------
__global__ __launch_bounds__(256)
void proj_heads(const float* __restrict__ PI, const float* __restrict__ V,
                const float* __restrict__ Wp, const float* __restrict__ bp,
                const float* __restrict__ Wv, const float* __restrict__ bv,
                float* __restrict__ logits, float* __restrict__ value) {
  __shared__ float pi_t[128][101];
  __shared__ float v_t[128][101];
  __shared__ float wp_s[100][18];
  __shared__ float wv_s[100];
  __shared__ float bp_s[18];
  __shared__ float bv_s;
  const int tid = threadIdx.x;
  const int R0 = blockIdx.x * 128;

  for (int idx = tid; idx < 12800; idx += 256) {
    int r = idx / 100, c = idx - r * 100;
    pi_t[r][c] = PI[(size_t)R0 * 100 + idx];
    v_t[r][c] = V[(size_t)R0 * 100 + idx];
  }
  for (int idx = tid; idx < 1800; idx += 256) ((float*)wp_s)[idx] = Wp[idx];
  if (tid < 100) wv_s[tid] = Wv[tid];
  if (tid < 18) bp_s[tid] = bp[tid];
  if (tid == 0) bv_s = bv[0];
  __syncthreads();

  const int r = tid >> 1, h = tid & 1;
  float acc[9];
#pragma unroll
  for (int m = 0; m < 9; ++m) acc[m] = bp_s[h * 9 + m];
  float vacc = bv_s;
#pragma unroll 4
  for (int c = 0; c < 100; ++c) {
    float p = pi_t[r][c];
#pragma unroll
    for (int m = 0; m < 9; ++m) acc[m] = fmaf(p, wp_s[c][h * 9 + m], acc[m]);
    if (h) vacc = fmaf(v_t[r][c], wv_s[c], vacc);
  }
  size_t t = (size_t)R0 + r;
#pragma unroll
  for (int m = 0; m < 9; ++m) logits[t * 18 + h * 9 + m] = acc[m];
  if (h) value[t] = vacc;
}

// ---------------------------------------------------------------------------
extern "C" void kernel_launch(void* const* d_in, const int* in_sizes, int n_in,
                              void* d_out, int out_size, void* d_ws, size_t ws_size,
                              hipStream_t stream) {
  const float* obs = (const float*)d_in[0];
  const float* W1  = (const float*)d_in[1];
  const float* b1  = (const float*)d_in[2];
  const float* Wg1 = (const float*)d_in[3];
  const float* bg1 = (const float*)d_in[4];
  const float* Wc1 = (const float*)d_in[5];
  const float* bc1 = (const float*)d_in[6];
  const float* Wg2 = (const float*)d_in[7];
  const float* bg2 = (const float*)d_in[8];
  const float* Wc2 = (const float*)d_in[9];
  const float* bc2 = (const float*)d_in[10];
  const float* W2  = (const float*)d_in[11];
  const float* b2  = (const float*)d_in[12];
  const float* W3  = (const float*)d_in[13];
  const float* b3  = (const float*)d_in[14];
  const float* Wp  = (const float*)d_in[15];
  const float* bp  = (const float*)d_in[16];
  const float* Wv  = (const float*)d_in[17];
  const float* bv  = (const float*)d_in[18];

  float* out = (float*)d_out;
  float* ws  = (float*)d_ws;
  const int T = T_STEPS;

  float* X   = ws + 0;
  float* A1  = ws + 8388608;
  float* C1X = ws + 25165824;
  float* H1  = ws + 33554432;
  float* A2  = ws + 0;
  float* C2X = ws + 16777216;
  float* YS  = ws + 33554432;
  float* PIb = ws + 0;
  float* Vb  = ws + 8388608;

  float* logits = out;
  float* value  = out + (size_t)T * 18;
  float* h1f    = out + (size_t)T * 18 + T;
  float* h2f    = h1f + 128;

  dim3 b256(256);
  // Parallel pre-pass: X = relu(obs@W1+b1); x-parts of GRU1 preactivations.
  gemm_k128<<<T / 32, b256, 0, stream>>>(obs, W1, b1, X, 128, 1);
  gemm_k128<<<T / 32, b256, 0, stream>>>(X, Wg1, bg1, A1, 256, 0);
  gemm_k128<<<T / 32, b256, 0, stream>>>(X, Wc1, bc1, C1X, 128, 0);
  // Sequential scan, GRU layer 1 -> H1 stream + final h1.
  gru_scan<<<1, b256, 0, stream>>>(A1, C1X, Wg1 + 128 * 256, Wc1 + 128 * 128, H1, h1f);
  // Parallel mid-pass: x-parts of GRU2 preactivations (input = H1).
  gemm_k128<<<T / 32, b256, 0, stream>>>(H1, Wg2, bg2, A2, 256, 0);
  gemm_k128<<<T / 32, b256, 0, stream>>>(H1, Wc2, bc2, C2X, 128, 0);
  // Sequential scan, GRU layer 2 -> YS stream + final h2.
  gru_scan<<<1, b256, 0, stream>>>(A2, C2X, Wg2 + 128 * 256, Wc2 + 128 * 128, YS, h2f);
  // Parallel heads.
  gemm_k128<<<T / 32, b256, 0, stream>>>(YS, W2, b2, PIb, 100, 1);
  gemm_k128<<<T / 32, b256, 0, stream>>>(YS, W3, b3, Vb, 100, 1);
  proj_heads<<<T / 128, b256, 0, stream>>>(PIb, Vb, Wp, bp, Wv, bv, logits, value);
}

// Round 3
// 100567.456 us; speedup vs baseline: 1.1852x; 1.1852x over previous
//
#include <hip/hip_runtime.h>

// Problem sizes (fixed).
#define T_STEPS 65536

typedef float f2 __attribute__((ext_vector_type(2)));
typedef float f4 __attribute__((ext_vector_type(4)));

__device__ __forceinline__ float sigmoid_f(float x) {
  float e = __expf(-x);
  return __builtin_amdgcn_rcpf(1.0f + e);
}
__device__ __forceinline__ float tanh_f(float x) {
  float e = __expf(-2.0f * x);
  return (1.0f - e) * __builtin_amdgcn_rcpf(1.0f + e);
}

// LDS-only barrier (no vmcnt drain; global prefetch stays in flight).
__device__ __forceinline__ void bar_lds() {
  asm volatile("s_waitcnt lgkmcnt(0)\n\ts_barrier" ::: "memory");
}

// Wave-uniform broadcast of lane `lane`'s value (VALU pipe, not LDS).
__device__ __forceinline__ float rdlane(float v, int lane) {
  return __int_as_float(__builtin_amdgcn_readlane(__float_as_int(v), lane));
}

// ---------------------------------------------------------------------------
// Generic K=128 GEMM: OUT[T][N] = act(IN[T][128] @ W[128][N] + bias[N])
// ---------------------------------------------------------------------------
__global__ __launch_bounds__(256)
void gemm_k128(const float* __restrict__ IN, const float* __restrict__ W,
               const float* __restrict__ bias, float* __restrict__ OUT,
               int N, int relu) {
  __shared__ __align__(16) float in_t[32][132];
  const int tid = threadIdx.x;
  const int ct = tid & 63;
  const int rt = tid >> 6;
  const int R0 = blockIdx.x * 32;

  const f4* src = (const f4*)(IN + (size_t)R0 * 128);
#pragma unroll
  for (int q = 0; q < 4; ++q) {
    int f4i = tid + 256 * q;
    int r = f4i >> 5, c4 = f4i & 31;
    f4 v = src[f4i];
    *(f4*)&in_t[r][c4 * 4] = v;
  }
  __syncthreads();

  f2 acc[8][4];
#pragma unroll
  for (int r = 0; r < 8; ++r)
#pragma unroll
    for (int m = 0; m < 4; ++m) acc[r][m] = (f2)0.0f;

  for (int kp = 0; kp < 64; ++kp) {
    f2 iv[8];
#pragma unroll
    for (int r = 0; r < 8; ++r)
      iv[r] = *(const f2*)&in_t[rt * 8 + r][2 * kp];
    f2 wv[4];
#pragma unroll
    for (int m = 0; m < 4; ++m) {
      int c = ct + 64 * m;
      if (c < N) {
        wv[m].x = W[(2 * kp) * N + c];
        wv[m].y = W[(2 * kp + 1) * N + c];
      } else {
        wv[m] = (f2)0.0f;
      }
    }
#pragma unroll
    for (int r = 0; r < 8; ++r)
#pragma unroll
      for (int m = 0; m < 4; ++m)
        acc[r][m] = __builtin_elementwise_fma(iv[r], wv[m], acc[r][m]);
  }

#pragma unroll
  for (int m = 0; m < 4; ++m) {
    int c = ct + 64 * m;
    if (c < N) {
      float b = bias[c];
#pragma unroll
      for (int r = 0; r < 8; ++r) {
        float v = acc[r][m].x + acc[r][m].y + b;
        if (relu) v = fmaxf(v, 0.0f);
        OUT[(size_t)(R0 + rt * 8 + r) * N + c] = v;
      }
    }
  }
}

// ---------------------------------------------------------------------------
// GRU scan, register-broadcast design ("Plan X").
// 256 threads = 4 waves. Lane-pair (j, j+32) of wave w OWNS state h[32w+j]
// (register hself, duplicated in both halves). Per step:
//   P1: gate partials for ALL 256 outputs over this wave's K-chunk [32w,32w+32)
//       -- chunk broadcast via v_readlane (VALU), pk_fma against 128 pinned
//       weight VGPRs; 4 partial writes to LDS (stride-5, conflict-free).
//   BAR1
//   P2: each lane reduces its r-output (o_r=32w+j) and u-output (o_r+128):
//       2x4 LDS reads + sigmoid; rh = r*hself stays IN REGISTER.
//   P3: cand partials for all 128 outputs over chunk (readlane of rh),
//       2 partial writes.
//   BAR2
//   P4: reduce c (4 reads) + tanh; h' = u*h + (1-u)*c in register; store hout.
// h / rh / u never touch LDS. 2 barriers/step, ~48 LDS instr/step per CU.
// ---------------------------------------------------------------------------
#define GRU_STEP(TT, AR, AU, CXV)                                             \
  do {                                                                        \
    f2 ga0 = (f2)0.0f, ga1 = (f2)0.0f, ga2 = (f2)0.0f, ga3 = (f2)0.0f;        \
    _Pragma("unroll")                                                         \
    for (int qq = 0; qq < 16; ++qq) {                                         \
      f2 hp;                                                                  \
      hp.x = rdlane(hself, 2 * qq);                                           \
      hp.y = rdlane(hself, 2 * qq + 1);                                       \
      ga0 = __builtin_elementwise_fma(hp, wgt[qq][0], ga0);                   \
      ga1 = __builtin_elementwise_fma(hp, wgt[qq][1], ga1);                   \
      ga2 = __builtin_elementwise_fma(hp, wgt[qq][2], ga2);                   \
      ga3 = __builtin_elementwise_fma(hp, wgt[qq][3], ga3);                   \
    }                                                                         \
    pg[(l + 0) * 5 + w] = ga0.x + ga0.y;                                      \
    pg[(l + 64) * 5 + w] = ga1.x + ga1.y;                                     \
    pg[(l + 128) * 5 + w] = ga2.x + ga2.y;                                    \
    pg[(l + 192) * 5 + w] = ga3.x + ga3.y;                                    \
    bar_lds();                                                                \
    float rpre = ((pg[o_r * 5 + 0] + pg[o_r * 5 + 1]) +                       \
                  (pg[o_r * 5 + 2] + pg[o_r * 5 + 3])) + (AR);                \
    float upre = ((pg[o_u * 5 + 0] + pg[o_u * 5 + 1]) +                       \
                  (pg[o_u * 5 + 2] + pg[o_u * 5 + 3])) + (AU);                \
    float rg = sigmoid_f(rpre);                                               \
    float ugv = sigmoid_f(upre);                                              \
    float rhv = rg * hself;                                                   \
    f2 ca0 = (f2)0.0f, ca1 = (f2)0.0f;                                        \
    _Pragma("unroll")                                                         \
    for (int qq = 0; qq < 16; ++qq) {                                         \
      f2 rp;                                                                  \
      rp.x = rdlane(rhv, 2 * qq);                                             \
      rp.y = rdlane(rhv, 2 * qq + 1);                                         \
      ca0 = __builtin_elementwise_fma(rp, wct[qq][0], ca0);                   \
      ca1 = __builtin_elementwise_fma(rp, wct[qq][1], ca1);                   \
    }                                                                         \
    pc[(l + 0) * 5 + w] = ca0.x + ca0.y;                                      \
    pc[(l + 64) * 5 + w] = ca1.x + ca1.y;                                     \
    bar_lds();                                                                \
    float cpre = ((pc[o_r * 5 + 0] + pc[o_r * 5 + 1]) +                       \
                  (pc[o_r * 5 + 2] + pc[o_r * 5 + 3])) + (CXV);               \
    float cv = tanh_f(cpre);                                                  \
    hself = ugv * hself + (1.0f - ugv) * cv;                                  \
    if (half == 0) hout[(size_t)(TT) * 128 + o_r] = hself;                    \
  } while (0)

__global__ __launch_bounds__(256, 1)
void gru_scan(const float* __restrict__ A,    // [T][256] x-part gate preacts (+bias)
              const float* __restrict__ CX,   // [T][128] x-part cand preacts (+bias)
              const float* __restrict__ Wgh,  // [128][256] h rows of gates kernel
              const float* __restrict__ Wch,  // [128][128] h rows of cand kernel
              float* __restrict__ hout,       // [T][128]
              float* __restrict__ hfinal) {   // [128]
  __shared__ float pg[256 * 5];  // gate partials, stride 5 (bank-conflict-free)
  __shared__ float pc[128 * 5];  // cand partials
  const int tid = threadIdx.x;
  const int w = tid >> 6;        // wave index
  const int l = tid & 63;        // lane
  const int j = l & 31;
  const int half = l >> 5;
  const int o_r = 32 * w + j;    // owned r / c / h element
  const int o_u = o_r + 128;     // owned u element

  // Pin weights: gate 32k x 4 outputs = 128 VGPR; cand 32k x 2 outputs = 64.
  f2 wgt[16][4];
  f2 wct[16][2];
#pragma unroll
  for (int q = 0; q < 16; ++q) {
#pragma unroll
    for (int m = 0; m < 4; ++m) {
      wgt[q][m].x = Wgh[(32 * w + 2 * q) * 256 + l + 64 * m];
      wgt[q][m].y = Wgh[(32 * w + 2 * q + 1) * 256 + l + 64 * m];
    }
#pragma unroll
    for (int n = 0; n < 2; ++n) {
      wct[q][n].x = Wch[(32 * w + 2 * q) * 128 + l + 64 * n];
      wct[q][n].y = Wch[(32 * w + 2 * q + 1) * 128 + l + 64 * n];
    }
  }

  float hself = 0.0f;  // owned recurrent-state element, lives in a VGPR

  // Per-thread global streams (prefetched 4 steps ahead).
  const float* Ar = A + o_r;
  const float* Au = A + o_u;
  const float* Cr = CX + o_r;

  float arc[4], auc[4], cxc[4], arn[4], aun[4], cxn[4];
#pragma unroll
  for (int q = 0; q < 4; ++q) {
    arc[q] = Ar[(size_t)q * 256];
    auc[q] = Au[(size_t)q * 256];
    cxc[q] = Cr[(size_t)q * 128];
  }

  for (int t0 = 0; t0 < T_STEPS; t0 += 4) {
    const size_t nb = (t0 + 4 < T_STEPS) ? (size_t)(t0 + 4) : 0;  // wrap: harmless
#pragma unroll
    for (int q = 0; q < 4; ++q) {
      arn[q] = Ar[(nb + q) * 256];
      aun[q] = Au[(nb + q) * 256];
      cxn[q] = Cr[(nb + q) * 128];
    }
#pragma unroll
    for (int q = 0; q < 4; ++q) {
      GRU_STEP(t0 + q, arc[q], auc[q], cxc[q]);
    }
#pragma unroll
    for (int q = 0; q < 4; ++q) { arc[q] = arn[q]; auc[q] = aun[q]; cxc[q] = cxn[q]; }
  }

  if (half == 0) hfinal[o_r] = hself;
}

// ---------------------------------------------------------------------------
// Final projections: logits = PI @ Wp + bp, value = V @ Wv + bv.
// ---------------------------------------------------------------------------
__global__ __launch_bounds__(256)
void proj_heads(const float* __restrict__ PI, const float* __restrict__ V,
                const float* __restrict__ Wp, const float* __restrict__ bp,
                const float* __restrict__ Wv, const float* __restrict__ bv,
                float* __restrict__ logits, float* __restrict__ value) {
  __shared__ float pi_t[128][101];
  __shared__ float v_t[128][101];
  __shared__ float wp_s[100][18];
  __shared__ float wv_s[100];
  __shared__ float bp_s[18];
  __shared__ float bv_s;
  const int tid = threadIdx.x;
  const int R0 = blockIdx.x * 128;

  for (int idx = tid; idx < 12800; idx += 256) {
    int r = idx / 100, c = idx - r * 100;
    pi_t[r][c] = PI[(size_t)R0 * 100 + idx];
    v_t[r][c] = V[(size_t)R0 * 100 + idx];
  }
  for (int idx = tid; idx < 1800; idx += 256) ((float*)wp_s)[idx] = Wp[idx];
  if (tid < 100) wv_s[tid] = Wv[tid];
  if (tid < 18) bp_s[tid] = bp[tid];
  if (tid == 0) bv_s = bv[0];
  __syncthreads();

  const int r = tid >> 1, h = tid & 1;
  float acc[9];
#pragma unroll
  for (int m = 0; m < 9; ++m) acc[m] = bp_s[h * 9 + m];
  float vacc = bv_s;
#pragma unroll 4
  for (int c = 0; c < 100; ++c) {
    float p = pi_t[r][c];
#pragma unroll
    for (int m = 0; m < 9; ++m) acc[m] = fmaf(p, wp_s[c][h * 9 + m], acc[m]);
    if (h) vacc = fmaf(v_t[r][c], wv_s[c], vacc);
  }
  size_t t = (size_t)R0 + r;
#pragma unroll
  for (int m = 0; m < 9; ++m) logits[t * 18 + h * 9 + m] = acc[m];
  if (h) value[t] = vacc;
}

// ---------------------------------------------------------------------------
extern "C" void kernel_launch(void* const* d_in, const int* in_sizes, int n_in,
                              void* d_out, int out_size, void* d_ws, size_t ws_size,
                              hipStream_t stream) {
  const float* obs = (const float*)d_in[0];
  const float* W1  = (const float*)d_in[1];
  const float* b1  = (const float*)d_in[2];
  const float* Wg1 = (const float*)d_in[3];
  const float* bg1 = (const float*)d_in[4];
  const float* Wc1 = (const float*)d_in[5];
  const float* bc1 = (const float*)d_in[6];
  const float* Wg2 = (const float*)d_in[7];
  const float* bg2 = (const float*)d_in[8];
  const float* Wc2 = (const float*)d_in[9];
  const float* bc2 = (const float*)d_in[10];
  const float* W2  = (const float*)d_in[11];
  const float* b2  = (const float*)d_in[12];
  const float* W3  = (const float*)d_in[13];
  const float* b3  = (const float*)d_in[14];
  const float* Wp  = (const float*)d_in[15];
  const float* bp  = (const float*)d_in[16];
  const float* Wv  = (const float*)d_in[17];
  const float* bv  = (const float*)d_in[18];

  float* out = (float*)d_out;
  float* ws  = (float*)d_ws;
  const int T = T_STEPS;

  float* X   = ws + 0;
  float* A1  = ws + 8388608;
  float* C1X = ws + 25165824;
  float* H1  = ws + 33554432;
  float* A2  = ws + 0;
  float* C2X = ws + 16777216;
  float* YS  = ws + 33554432;
  float* PIb = ws + 0;
  float* Vb  = ws + 8388608;

  float* logits = out;
  float* value  = out + (size_t)T * 18;
  float* h1f    = out + (size_t)T * 18 + T;
  float* h2f    = h1f + 128;

  dim3 b256(256);
  // Parallel pre-pass: X = relu(obs@W1+b1); x-parts of GRU1 preactivations.
  gemm_k128<<<T / 32, b256, 0, stream>>>(obs, W1, b1, X, 128, 1);
  gemm_k128<<<T / 32, b256, 0, stream>>>(X, Wg1, bg1, A1, 256, 0);
  gemm_k128<<<T / 32, b256, 0, stream>>>(X, Wc1, bc1, C1X, 128, 0);
  // Sequential scan, GRU layer 1 -> H1 stream + final h1.
  gru_scan<<<1, b256, 0, stream>>>(A1, C1X, Wg1 + 128 * 256, Wc1 + 128 * 128, H1, h1f);
  // Parallel mid-pass: x-parts of GRU2 preactivations (input = H1).
  gemm_k128<<<T / 32, b256, 0, stream>>>(H1, Wg2, bg2, A2, 256, 0);
  gemm_k128<<<T / 32, b256, 0, stream>>>(H1, Wc2, bc2, C2X, 128, 0);
  // Sequential scan, GRU layer 2 -> YS stream + final h2.
  gru_scan<<<1, b256, 0, stream>>>(A2, C2X, Wg2 + 128 * 256, Wc2 + 128 * 128, YS, h2f);
  // Parallel heads.
  gemm_k128<<<T / 32, b256, 0, stream>>>(YS, W2, b2, PIb, 100, 1);
  gemm_k128<<<T / 32, b256, 0, stream>>>(YS, W3, b3, Vb, 100, 1);
  proj_heads<<<T / 128, b256, 0, stream>>>(PIb, Vb, Wp, bp, Wv, bv, logits, value);
}